// Round 12
// baseline (284.523 us; speedup 1.0000x reference)
//
#include <hip/hip_runtime.h>
#include <math.h>

#define FDIM 256
#define NEG_SLOPE 0.2f

typedef _Float16 half2v __attribute__((ext_vector_type(2)));
typedef _Float16 half4v __attribute__((ext_vector_type(4)));
typedef _Float16 half8v __attribute__((ext_vector_type(8)));
typedef float f32x4 __attribute__((ext_vector_type(4)));

// ---- phase1: pos-graph histogram by dst + weight split prep ---------------

__global__ void build_phase1(const int* __restrict__ pos_ei,
                             int* __restrict__ cnt,
                             const float* __restrict__ W0, const float* __restrict__ W1,
                             const float* __restrict__ W2,
                             _Float16* __restrict__ Wt_hi, _Float16* __restrict__ Wt_lo,
                             int E_pos, int E_tot, int nbE) {
    int b = blockIdx.x;
    int tid = threadIdx.x;
    if (b < nbE) {
        int e = b * 256 + tid;
        if (e < E_tot) {
            int d = (e < E_pos) ? pos_ei[E_pos + e] : (e - E_pos);
            atomicAdd(&cnt[d], 1);
        }
    } else {
        int idx = b - nbE;                // 0..767
        int n = idx & 255, mat = idx >> 8;
        const float* W = (mat == 0) ? W0 : (mat == 1) ? W1 : W2;
        int k = tid;
        float v = W[k * FDIM + n];
        _Float16 hi = (_Float16)v;
        _Float16 lo = (_Float16)(v - (float)hi);
        size_t o = (size_t)mat * FDIM * FDIM + (size_t)n * FDIM + k;
        Wt_hi[o] = hi;
        Wt_lo[o] = lo;
    }
}

// ------- split-f16 MFMA GEMM + sidecar blocks ------------------------------
// MODE 0: A fp32 (inline split), C = split f16 (hi/lo) + bias; sidecar = scan
// MODE 1: A pre-split f16, C = f16, fused attn projections; sidecar = scatter

template <int MODE>
__global__ __launch_bounds__(256) void gemm_mfma(
        const float* __restrict__ A32,
        const _Float16* __restrict__ A_hi, const _Float16* __restrict__ A_lo,
        const _Float16* __restrict__ Bt_hi, const _Float16* __restrict__ Bt_lo,
        const float* __restrict__ bias,
        const float* __restrict__ a_src, const float* __restrict__ a_dst,
        float* __restrict__ al_s, float* __restrict__ al_d,
        _Float16* __restrict__ C_hi, _Float16* __restrict__ C_lo,
        int M, int nbGemm, int mblk,
        const int* __restrict__ pos_ei, int* __restrict__ cnt_or_fill,
        int* __restrict__ row_ptr, int* __restrict__ fill_or_srcs,
        int E_pos, int E_tot, int N) {
    __shared__ _Float16 As_hi[64][72];
    __shared__ _Float16 As_lo[64][72];
    __shared__ _Float16 Bs_hi[64][72];
    __shared__ _Float16 Bs_lo[64][72];
    int b = blockIdx.x;
    int tid = threadIdx.x;

    if (b >= nbGemm) {
        if (MODE == 0) {
            int* sums = (int*)&As_hi[0][0];
            const int CH = 40;
            const int* cnt = cnt_or_fill;
            int base = tid * CH;
            int s = 0;
            for (int i = 0; i < CH; ++i) {
                int idx = base + i;
                s += (idx < N) ? cnt[idx] : 0;
            }
            sums[tid] = s;
            __syncthreads();
            for (int off = 1; off < 256; off <<= 1) {
                int v = (tid >= off) ? sums[tid - off] : 0;
                __syncthreads();
                sums[tid] += v;
                __syncthreads();
            }
            int run = (tid == 0) ? 0 : sums[tid - 1];
            for (int i = 0; i < CH; ++i) {
                int idx = base + i;
                if (idx < N) {
                    int v = cnt[idx];
                    row_ptr[idx] = run;
                    fill_or_srcs[idx] = run;
                    run += v;
                }
            }
            if (tid == 255) row_ptr[N] = sums[255];
        } else {
            int e = (b - nbGemm) * 256 + tid;
            if (e < E_tot) {
                int s, d;
                if (e < E_pos) { s = pos_ei[e]; d = pos_ei[E_pos + e]; }
                else           { s = e - E_pos; d = s; }
                int pos = atomicAdd(&cnt_or_fill[d], 1);
                fill_or_srcs[pos] = s;
            }
        }
        return;
    }

    int lane = tid & 63, w = tid >> 6;
    int wm = w >> 1, wn = w & 1;
    int quad = lane >> 4, l16 = lane & 15;
    int bx = b % mblk, by = b / mblk;
    int mBase = bx * 64, nBase = by * 64;
    f32x4 acc[2][2] = {};

    for (int k0 = 0; k0 < FDIM; k0 += 64) {
        __syncthreads();
        if (MODE == 0) {
#pragma unroll
            for (int i = 0; i < 4; ++i) {
                int f = tid + i * 256;
                int m = f >> 4, kc = (f & 15) << 2;
                int row = mBase + m;
                float4 a = make_float4(0.f, 0.f, 0.f, 0.f);
                if (row < M) a = *(const float4*)(A32 + (size_t)row * FDIM + k0 + kc);
                _Float16 hx = (_Float16)a.x, hy = (_Float16)a.y;
                _Float16 hz = (_Float16)a.z, hw = (_Float16)a.w;
                half4v hi = {hx, hy, hz, hw};
                half4v lo = {(_Float16)(a.x - (float)hx), (_Float16)(a.y - (float)hy),
                             (_Float16)(a.z - (float)hz), (_Float16)(a.w - (float)hw)};
                *(half4v*)&As_hi[m][kc] = hi;
                *(half4v*)&As_lo[m][kc] = lo;
            }
        } else {
#pragma unroll
            for (int i = 0; i < 2; ++i) {
                int g = tid + i * 256;
                int m = g >> 3, gk = (g & 7) << 3;
                int row = mBase + m;
                half8v hi, lo;
                if (row < M) {
                    size_t off = (size_t)row * FDIM + k0 + gk;
                    hi = *(const half8v*)(A_hi + off);
                    lo = *(const half8v*)(A_lo + off);
                } else {
                    _Float16 z = (_Float16)0.f;
                    hi = (half8v){z, z, z, z, z, z, z, z};
                    lo = hi;
                }
                *(half8v*)&As_hi[m][gk] = hi;
                *(half8v*)&As_lo[m][gk] = lo;
            }
        }
#pragma unroll
        for (int i = 0; i < 2; ++i) {
            int g = tid + i * 256;
            int n = g >> 3, gk = (g & 7) << 3;
            size_t off = (size_t)(nBase + n) * FDIM + k0 + gk;
            *(half8v*)&Bs_hi[n][gk] = *(const half8v*)(Bt_hi + off);
            *(half8v*)&Bs_lo[n][gk] = *(const half8v*)(Bt_lo + off);
        }
        __syncthreads();
#pragma unroll
        for (int ks = 0; ks < 2; ++ks) {
            int kcol = ks * 32 + quad * 8;
            half8v aHi[2], aLo[2], bHi[2], bLo[2];
#pragma unroll
            for (int mt = 0; mt < 2; ++mt) {
                int r = wm * 32 + mt * 16 + l16;
                aHi[mt] = *(const half8v*)&As_hi[r][kcol];
                aLo[mt] = *(const half8v*)&As_lo[r][kcol];
            }
#pragma unroll
            for (int nt = 0; nt < 2; ++nt) {
                int c = wn * 32 + nt * 16 + l16;
                bHi[nt] = *(const half8v*)&Bs_hi[c][kcol];
                bLo[nt] = *(const half8v*)&Bs_lo[c][kcol];
            }
#pragma unroll
            for (int mt = 0; mt < 2; ++mt)
#pragma unroll
                for (int nt = 0; nt < 2; ++nt) {
                    acc[mt][nt] = __builtin_amdgcn_mfma_f32_16x16x32_f16(
                        aHi[mt], bHi[nt], acc[mt][nt], 0, 0, 0);
                    acc[mt][nt] = __builtin_amdgcn_mfma_f32_16x16x32_f16(
                        aHi[mt], bLo[nt], acc[mt][nt], 0, 0, 0);
                    acc[mt][nt] = __builtin_amdgcn_mfma_f32_16x16x32_f16(
                        aLo[mt], bHi[nt], acc[mt][nt], 0, 0, 0);
                }
        }
    }

    int col0 = nBase + wn * 32 + l16;
    int col1 = col0 + 16;
    if (MODE == 0) {
        float b0 = bias[col0], b1v = bias[col1];
#pragma unroll
        for (int mt = 0; mt < 2; ++mt) {
#pragma unroll
            for (int r = 0; r < 4; ++r) {
                int row = mBase + wm * 32 + mt * 16 + quad * 4 + r;
                if (row >= M) continue;
                float o0 = acc[mt][0][r] + b0;
                float o1 = acc[mt][1][r] + b1v;
                _Float16 h0 = (_Float16)o0, h1 = (_Float16)o1;
                size_t p0 = (size_t)row * FDIM + col0;
                size_t p1 = (size_t)row * FDIM + col1;
                C_hi[p0] = h0;              C_hi[p1] = h1;
                C_lo[p0] = (_Float16)(o0 - (float)h0);
                C_lo[p1] = (_Float16)(o1 - (float)h1);
            }
        }
    } else {
        float as0 = a_src[col0], as1 = a_src[col1];
        float ad0 = a_dst[col0], ad1 = a_dst[col1];
#pragma unroll
        for (int mt = 0; mt < 2; ++mt) {
#pragma unroll
            for (int r = 0; r < 4; ++r) {
                int row = mBase + wm * 32 + mt * 16 + quad * 4 + r;
                if (row < M) {
                    C_hi[(size_t)row * FDIM + col0] = (_Float16)acc[mt][0][r];
                    C_hi[(size_t)row * FDIM + col1] = (_Float16)acc[mt][1][r];
                }
                float ps = acc[mt][0][r] * as0 + acc[mt][1][r] * as1;
                float pd = acc[mt][0][r] * ad0 + acc[mt][1][r] * ad1;
#pragma unroll
                for (int off = 8; off; off >>= 1) {
                    ps += __shfl_xor(ps, off);
                    pd += __shfl_xor(pd, off);
                }
                if (l16 == 0 && row < M) {
                    atomicAdd(&al_s[row], ps);
                    atomicAdd(&al_d[row], pd);
                }
            }
        }
    }
}

// ------- generic per-node softmax+aggregate (rare: deg > 64) ---------------

__device__ __forceinline__ void agg_node_generic(
        const _Float16* __restrict__ t, const float* __restrict__ al_s,
        const int* __restrict__ srcs, int beg, int end, float ad, int lane,
        float4& acc, float& ssum) {
    const half4v* tb = (const half4v*)t + lane;
    float m = -INFINITY;
    for (int j = beg + lane; j < end; j += 64) {
        float ee = al_s[srcs[j]] + ad;
        ee = (ee > 0.f) ? ee : NEG_SLOPE * ee;
        m = fmaxf(m, ee);
    }
#pragma unroll
    for (int o = 32; o; o >>= 1) m = fmaxf(m, __shfl_xor(m, o));
    for (int jc = beg; jc < end; jc += 64) {
        int j = jc + lane;
        float ex = 0.f;
        int sr = 0;
        if (j < end) {
            int s = srcs[j];
            float ee = al_s[s] + ad;
            ee = (ee > 0.f) ? ee : NEG_SLOPE * ee;
            ex = __expf(ee - m);
            ssum += ex;
            sr = s * 64;
        }
        int cnt = min(64, end - jc);
        for (int jj = 0; jj < cnt; ++jj) {
            float a = __shfl(ex, jj);
            int r = __shfl(sr, jj);
            half4v v = tb[r];
            acc.x = fmaf(a, (float)v.x, acc.x); acc.y = fmaf(a, (float)v.y, acc.y);
            acc.z = fmaf(a, (float)v.z, acc.z); acc.w = fmaf(a, (float)v.w, acc.w);
        }
    }
}

// ------- fused edge-softmax + aggregation: 4 NODES PER WAVE ----------------
// 2500 waves total; four independent gather chains interleaved 4-edge-group
// wise -> up to 16 loads in flight. Fast path needs deg<=64 per node
// (P(deg>64) ~ 3e-8 at mean 33); per-node op order matches round 11's
// deg<=64 case -> bit-identical output.

__global__ __launch_bounds__(256) void softagg(
        const _Float16* __restrict__ t, const float* __restrict__ al_s,
        const float* __restrict__ al_d, const int* __restrict__ row_ptr,
        const int* __restrict__ srcs, const float* __restrict__ bias,
        _Float16* __restrict__ out_hi, _Float16* __restrict__ out_lo, int N) {
    int wave = threadIdx.x >> 6, lane = threadIdx.x & 63;
    int node0 = (blockIdx.x * 4 + wave) * 4;
    if (node0 >= N) return;
    int nn = min(4, N - node0);

    // contiguous row_ptr slice
    int rp[5];
#pragma unroll
    for (int c = 0; c <= 4; ++c) rp[c] = row_ptr[min(node0 + c, N)];
    int deg[4];
    bool fast = (nn == 4);
#pragma unroll
    for (int c = 0; c < 4; ++c) {
        deg[c] = rp[c + 1] - rp[c];
        if (deg[c] > 64) fast = false;
    }

    const half4v* tb = (const half4v*)t + lane;
    float4 acc[4];
    float ssum[4];
#pragma unroll
    for (int c = 0; c < 4; ++c) {
        acc[c] = make_float4(0.f, 0.f, 0.f, 0.f);
        ssum[c] = 0.f;
    }

    if (fast) {
        float ad[4], e[4];
        int sj[4];
#pragma unroll
        for (int c = 0; c < 4; ++c) ad[c] = al_d[node0 + c];
#pragma unroll
        for (int c = 0; c < 4; ++c) {
            e[c] = -INFINITY; sj[c] = 0;
            int j = rp[c] + lane;
            if (j < rp[c + 1]) {
                int s = srcs[j];
                float ee = al_s[s] + ad[c];
                e[c] = (ee > 0.f) ? ee : NEG_SLOPE * ee;
                sj[c] = s * 64;
            }
        }
        float m[4];
#pragma unroll
        for (int c = 0; c < 4; ++c) m[c] = e[c];
#pragma unroll
        for (int o = 32; o; o >>= 1) {
#pragma unroll
            for (int c = 0; c < 4; ++c) m[c] = fmaxf(m[c], __shfl_xor(m[c], o));
        }
        float ex[4];
#pragma unroll
        for (int c = 0; c < 4; ++c) {
            ex[c] = (e[c] == -INFINITY) ? 0.f : __expf(e[c] - m[c]);
            ssum[c] += ex[c];
        }

        int ng[4], ngMax = 0;
#pragma unroll
        for (int c = 0; c < 4; ++c) {
            ng[c] = (deg[c] + 3) >> 2;
            ngMax = max(ngMax, ng[c]);
        }
        for (int g = 0; g < ngMax; ++g) {
            int jj = g * 4;
            float a[4][4];
            int r[4][4];
            half4v v[4][4];
#pragma unroll
            for (int c = 0; c < 4; ++c) {
                if (g < ng[c]) {
#pragma unroll
                    for (int q = 0; q < 4; ++q) {
                        a[c][q] = __shfl(ex[c], jj + q);
                        r[c][q] = __shfl(sj[c], jj + q);
                    }
                }
            }
#pragma unroll
            for (int c = 0; c < 4; ++c) {
                if (g < ng[c]) {
#pragma unroll
                    for (int q = 0; q < 4; ++q) v[c][q] = tb[r[c][q]];
                }
            }
#pragma unroll
            for (int c = 0; c < 4; ++c) {
                if (g < ng[c]) {
#pragma unroll
                    for (int q = 0; q < 4; ++q) {
                        acc[c].x = fmaf(a[c][q], (float)v[c][q].x, acc[c].x);
                        acc[c].y = fmaf(a[c][q], (float)v[c][q].y, acc[c].y);
                        acc[c].z = fmaf(a[c][q], (float)v[c][q].z, acc[c].z);
                        acc[c].w = fmaf(a[c][q], (float)v[c][q].w, acc[c].w);
                    }
                }
            }
        }
    } else {
        for (int c = 0; c < nn; ++c) {
            float ad = al_d[node0 + c];
            agg_node_generic(t, al_s, srcs, rp[c], rp[c + 1], ad, lane,
                             acc[c], ssum[c]);
        }
    }

#pragma unroll
    for (int o = 32; o; o >>= 1) {
#pragma unroll
        for (int c = 0; c < 4; ++c) ssum[c] += __shfl_xor(ssum[c], o);
    }
    float4 bv = ((const float4*)bias)[lane];
    for (int c = 0; c < nn; ++c) {
        float inv = 1.f / (ssum[c] + 1e-16f);
        float ox = fmaf(acc[c].x, inv, bv.x);
        float oy = fmaf(acc[c].y, inv, bv.y);
        float oz = fmaf(acc[c].z, inv, bv.z);
        float ow = fmaf(acc[c].w, inv, bv.w);
        _Float16 hx = (_Float16)ox, hy = (_Float16)oy;
        _Float16 hz = (_Float16)oz, hw = (_Float16)ow;
        half4v hi = {hx, hy, hz, hw};
        int node = node0 + c;
        *(half4v*)(out_hi + (size_t)node * FDIM + lane * 4) = hi;
        if (out_lo) {
            half4v lo = {(_Float16)(ox - (float)hx), (_Float16)(oy - (float)hy),
                         (_Float16)(oz - (float)hz), (_Float16)(ow - (float)hw)};
            *(half4v*)(out_lo + (size_t)node * FDIM + lane * 4) = lo;
        }
    }
}

// -------- logits: 8 edges per wave, f16 h rows (half4/lane) ----------------

__global__ __launch_bounds__(256) void edge_dot(const _Float16* __restrict__ h,
                                                const int* __restrict__ ei,
                                                float* __restrict__ out, int EQ) {
    int w = threadIdx.x >> 6, lane = threadIdx.x & 63;
    int e0 = (blockIdx.x * 4 + w) * 8;
    if (e0 >= EQ) return;
    int u[8], v[8];
    if (e0 + 7 < EQ) {
        int4 uu0 = *(const int4*)(ei + e0);
        int4 uu1 = *(const int4*)(ei + e0 + 4);
        int4 vv0 = *(const int4*)(ei + EQ + e0);
        int4 vv1 = *(const int4*)(ei + EQ + e0 + 4);
        u[0] = uu0.x; u[1] = uu0.y; u[2] = uu0.z; u[3] = uu0.w;
        u[4] = uu1.x; u[5] = uu1.y; u[6] = uu1.z; u[7] = uu1.w;
        v[0] = vv0.x; v[1] = vv0.y; v[2] = vv0.z; v[3] = vv0.w;
        v[4] = vv1.x; v[5] = vv1.y; v[6] = vv1.z; v[7] = vv1.w;
    } else {
#pragma unroll
        for (int q = 0; q < 8; ++q) {
            int e = min(e0 + q, EQ - 1);
            u[q] = ei[e];
            v[q] = ei[EQ + e];
        }
    }
    const half4v* hb = (const half4v*)h + lane;
    float s[8];
#pragma unroll
    for (int half = 0; half < 2; ++half) {
        half4v a[4], b[4];
#pragma unroll
        for (int q = 0; q < 4; ++q) {
            a[q] = hb[(size_t)u[half * 4 + q] * 64];
            b[q] = hb[(size_t)v[half * 4 + q] * 64];
        }
#pragma unroll
        for (int q = 0; q < 4; ++q) {
            s[half * 4 + q] =
                (float)a[q].x * (float)b[q].x + (float)a[q].y * (float)b[q].y +
                (float)a[q].z * (float)b[q].z + (float)a[q].w * (float)b[q].w;
        }
    }
#pragma unroll
    for (int o = 32; o; o >>= 1) {
#pragma unroll
        for (int q = 0; q < 8; ++q) s[q] += __shfl_down(s[q], o);
    }
    if (lane == 0) {
#pragma unroll
        for (int q = 0; q < 8; ++q)
            if (e0 + q < EQ) out[e0 + q] = s[q];
    }
}

// ---------------------------------------------------------------------------

extern "C" void kernel_launch(void* const* d_in, const int* in_sizes, int n_in,
                              void* d_out, int out_size, void* d_ws, size_t ws_size,
                              hipStream_t stream) {
    const float* x       = (const float*)d_in[0];
    const int*   pos_ei  = (const int*)d_in[1];
    const int*   q_ei    = (const int*)d_in[2];
    const float* Win_W   = (const float*)d_in[3];
    const float* Win_b   = (const float*)d_in[4];
    const float* W1      = (const float*)d_in[5];
    const float* a1_src  = (const float*)d_in[6];
    const float* a1_dst  = (const float*)d_in[7];
    const float* b1      = (const float*)d_in[8];
    const float* W2      = (const float*)d_in[9];
    const float* a2_src  = (const float*)d_in[10];
    const float* a2_dst  = (const float*)d_in[11];
    const float* b2      = (const float*)d_in[12];
    float* logits = (float*)d_out;

    const int N = in_sizes[0] / FDIM;   // 10000
    const int E_pos = in_sizes[1] / 2;  // 320000
    const int EQ = in_sizes[2] / 2;     // 100000
    const int E_tot = E_pos + N;        // 330000
    const size_t WMAT = (size_t)FDIM * FDIM;
    const size_t NF = (size_t)N * FDIM;

    // workspace carve-up
    _Float16* Wt_hi = (_Float16*)d_ws;          // 3*WMAT
    _Float16* Wt_lo = Wt_hi + 3 * WMAT;         // 3*WMAT
    _Float16* h0_hi = Wt_lo + 3 * WMAT;         // NF (also o2_hi)
    _Float16* h0_lo = h0_hi + NF;               // NF (also o2_lo)
    _Float16* t_h   = h0_lo + NF;               // NF
    _Float16* h16   = t_h + NF;                 // NF f16 (final h for edge_dot)
    float* al_s1 = (float*)(h16 + NF);          // N -- zero region start
    float* al_d1 = al_s1 + N;                   // N
    float* al_s2 = al_d1 + N;                   // N
    float* al_d2 = al_s2 + N;                   // N
    int* cnt     = (int*)(al_d2 + N);           // N -- zero region end
    int* row_ptr = cnt + N;                     // N+1
    int* fill    = row_ptr + (N + 1);           // N
    int* srcs    = fill + N;                    // E_tot

    hipMemsetAsync(al_s1, 0, (size_t)(4 * N) * sizeof(float) + (size_t)N * sizeof(int), stream);

    int nbE = (E_tot + 255) / 256;      // 1290
    int mblk = (N + 63) / 64;           // 157
    int nbGemm = mblk * (FDIM / 64);    // 628
    int nblk16 = (N + 15) / 16;         // 625  (4 waves x 4 nodes per block)

    // ---- D1: histogram + weight prep ----
    build_phase1<<<nbE + 768, 256, 0, stream>>>(pos_ei, cnt, Win_W, W1, W2,
                                                Wt_hi, Wt_lo, E_pos, E_tot, nbE);

    // ---- D2: gemm<0> (h0 = x @ Win + b) + sidecar CSR scan ----
    gemm_mfma<0><<<nbGemm + 1, 256, 0, stream>>>(
        x, nullptr, nullptr, Wt_hi, Wt_lo, Win_b,
        nullptr, nullptr, nullptr, nullptr, h0_hi, h0_lo,
        N, nbGemm, mblk,
        pos_ei, cnt, row_ptr, fill, E_pos, E_tot, N);

    // ---- D3: gemm<1> L1 (t = h0 @ W1, attn -> al1) + sidecar edge scatter ----
    gemm_mfma<1><<<nbGemm + nbE, 256, 0, stream>>>(
        nullptr, h0_hi, h0_lo, Wt_hi + WMAT, Wt_lo + WMAT, nullptr,
        a1_src, a1_dst, al_s1, al_d1, t_h, nullptr,
        N, nbGemm, mblk,
        pos_ei, fill, nullptr, srcs, E_pos, E_tot, N);

    // ---- D4: softagg L1 -> o2 split (aliases h0), 4 nodes/wave ----
    softagg<<<nblk16, 256, 0, stream>>>(t_h, al_s1, al_d1, row_ptr, srcs, b1,
                                        h0_hi, h0_lo, N);

    // ---- D5: gemm<1> L2 (t = o2 @ W2, attn -> al2) ----
    gemm_mfma<1><<<nbGemm, 256, 0, stream>>>(
        nullptr, h0_hi, h0_lo, Wt_hi + 2 * WMAT, Wt_lo + 2 * WMAT, nullptr,
        a2_src, a2_dst, al_s2, al_d2, t_h, nullptr,
        N, nbGemm, mblk,
        nullptr, nullptr, nullptr, nullptr, 0, 0, N);

    // ---- D6: softagg L2 -> h16 (plain f16), 4 nodes/wave ----
    softagg<<<nblk16, 256, 0, stream>>>(t_h, al_s2, al_d2, row_ptr, srcs, b2,
                                        h16, nullptr, N);

    // ---- D7: logits (8 edges/wave, f16 rows) ----
    edge_dot<<<(EQ + 31) / 32, 256, 0, stream>>>(h16, q_ei, logits, EQ);
}

// Round 13
// 225.361 us; speedup vs baseline: 1.2625x; 1.2625x over previous
//
#include <hip/hip_runtime.h>
#include <math.h>

#define FDIM 256
#define NEG_SLOPE 0.2f

typedef _Float16 half2v __attribute__((ext_vector_type(2)));
typedef _Float16 half4v __attribute__((ext_vector_type(4)));
typedef _Float16 half8v __attribute__((ext_vector_type(8)));
typedef float f32x4 __attribute__((ext_vector_type(4)));

// ---- phase1: pos-graph histogram by dst + weight split prep ---------------

__global__ void build_phase1(const int* __restrict__ pos_ei,
                             int* __restrict__ cnt,
                             const float* __restrict__ W0, const float* __restrict__ W1,
                             const float* __restrict__ W2,
                             _Float16* __restrict__ Wt_hi, _Float16* __restrict__ Wt_lo,
                             int E_pos, int E_tot, int nbE) {
    int b = blockIdx.x;
    int tid = threadIdx.x;
    if (b < nbE) {
        int e = b * 256 + tid;
        if (e < E_tot) {
            int d = (e < E_pos) ? pos_ei[E_pos + e] : (e - E_pos);
            atomicAdd(&cnt[d], 1);
        }
    } else {
        int idx = b - nbE;                // 0..767
        int n = idx & 255, mat = idx >> 8;
        const float* W = (mat == 0) ? W0 : (mat == 1) ? W1 : W2;
        int k = tid;
        float v = W[k * FDIM + n];
        _Float16 hi = (_Float16)v;
        _Float16 lo = (_Float16)(v - (float)hi);
        size_t o = (size_t)mat * FDIM * FDIM + (size_t)n * FDIM + k;
        Wt_hi[o] = hi;
        Wt_lo[o] = lo;
    }
}

// ------- split-f16 MFMA GEMM + sidecar blocks ------------------------------
// MODE 0: A fp32 (inline split), C = split f16 (hi/lo) + bias; sidecar = scan
// MODE 1: A pre-split f16, C = f16, fused attn projections; sidecar = scatter

template <int MODE>
__global__ __launch_bounds__(256) void gemm_mfma(
        const float* __restrict__ A32,
        const _Float16* __restrict__ A_hi, const _Float16* __restrict__ A_lo,
        const _Float16* __restrict__ Bt_hi, const _Float16* __restrict__ Bt_lo,
        const float* __restrict__ bias,
        const float* __restrict__ a_src, const float* __restrict__ a_dst,
        float* __restrict__ al_s, float* __restrict__ al_d,
        _Float16* __restrict__ C_hi, _Float16* __restrict__ C_lo,
        int M, int nbGemm, int mblk,
        const int* __restrict__ pos_ei, int* __restrict__ cnt_or_fill,
        int* __restrict__ row_ptr, int* __restrict__ fill_or_srcs,
        int E_pos, int E_tot, int N) {
    __shared__ _Float16 As_hi[64][72];
    __shared__ _Float16 As_lo[64][72];
    __shared__ _Float16 Bs_hi[64][72];
    __shared__ _Float16 Bs_lo[64][72];
    int b = blockIdx.x;
    int tid = threadIdx.x;

    if (b >= nbGemm) {
        if (MODE == 0) {
            int* sums = (int*)&As_hi[0][0];
            const int CH = 40;
            const int* cnt = cnt_or_fill;
            int base = tid * CH;
            int s = 0;
            for (int i = 0; i < CH; ++i) {
                int idx = base + i;
                s += (idx < N) ? cnt[idx] : 0;
            }
            sums[tid] = s;
            __syncthreads();
            for (int off = 1; off < 256; off <<= 1) {
                int v = (tid >= off) ? sums[tid - off] : 0;
                __syncthreads();
                sums[tid] += v;
                __syncthreads();
            }
            int run = (tid == 0) ? 0 : sums[tid - 1];
            for (int i = 0; i < CH; ++i) {
                int idx = base + i;
                if (idx < N) {
                    int v = cnt[idx];
                    row_ptr[idx] = run;
                    fill_or_srcs[idx] = run;
                    run += v;
                }
            }
            if (tid == 255) row_ptr[N] = sums[255];
        } else {
            int e = (b - nbGemm) * 256 + tid;
            if (e < E_tot) {
                int s, d;
                if (e < E_pos) { s = pos_ei[e]; d = pos_ei[E_pos + e]; }
                else           { s = e - E_pos; d = s; }
                int pos = atomicAdd(&cnt_or_fill[d], 1);
                fill_or_srcs[pos] = s;
            }
        }
        return;
    }

    int lane = tid & 63, w = tid >> 6;
    int wm = w >> 1, wn = w & 1;
    int quad = lane >> 4, l16 = lane & 15;
    int bx = b % mblk, by = b / mblk;
    int mBase = bx * 64, nBase = by * 64;
    f32x4 acc[2][2] = {};

    for (int k0 = 0; k0 < FDIM; k0 += 64) {
        __syncthreads();
        if (MODE == 0) {
#pragma unroll
            for (int i = 0; i < 4; ++i) {
                int f = tid + i * 256;
                int m = f >> 4, kc = (f & 15) << 2;
                int row = mBase + m;
                float4 a = make_float4(0.f, 0.f, 0.f, 0.f);
                if (row < M) a = *(const float4*)(A32 + (size_t)row * FDIM + k0 + kc);
                _Float16 hx = (_Float16)a.x, hy = (_Float16)a.y;
                _Float16 hz = (_Float16)a.z, hw = (_Float16)a.w;
                half4v hi = {hx, hy, hz, hw};
                half4v lo = {(_Float16)(a.x - (float)hx), (_Float16)(a.y - (float)hy),
                             (_Float16)(a.z - (float)hz), (_Float16)(a.w - (float)hw)};
                *(half4v*)&As_hi[m][kc] = hi;
                *(half4v*)&As_lo[m][kc] = lo;
            }
        } else {
#pragma unroll
            for (int i = 0; i < 2; ++i) {
                int g = tid + i * 256;
                int m = g >> 3, gk = (g & 7) << 3;
                int row = mBase + m;
                half8v hi, lo;
                if (row < M) {
                    size_t off = (size_t)row * FDIM + k0 + gk;
                    hi = *(const half8v*)(A_hi + off);
                    lo = *(const half8v*)(A_lo + off);
                } else {
                    _Float16 z = (_Float16)0.f;
                    hi = (half8v){z, z, z, z, z, z, z, z};
                    lo = hi;
                }
                *(half8v*)&As_hi[m][gk] = hi;
                *(half8v*)&As_lo[m][gk] = lo;
            }
        }
#pragma unroll
        for (int i = 0; i < 2; ++i) {
            int g = tid + i * 256;
            int n = g >> 3, gk = (g & 7) << 3;
            size_t off = (size_t)(nBase + n) * FDIM + k0 + gk;
            *(half8v*)&Bs_hi[n][gk] = *(const half8v*)(Bt_hi + off);
            *(half8v*)&Bs_lo[n][gk] = *(const half8v*)(Bt_lo + off);
        }
        __syncthreads();
#pragma unroll
        for (int ks = 0; ks < 2; ++ks) {
            int kcol = ks * 32 + quad * 8;
            half8v aHi[2], aLo[2], bHi[2], bLo[2];
#pragma unroll
            for (int mt = 0; mt < 2; ++mt) {
                int r = wm * 32 + mt * 16 + l16;
                aHi[mt] = *(const half8v*)&As_hi[r][kcol];
                aLo[mt] = *(const half8v*)&As_lo[r][kcol];
            }
#pragma unroll
            for (int nt = 0; nt < 2; ++nt) {
                int c = wn * 32 + nt * 16 + l16;
                bHi[nt] = *(const half8v*)&Bs_hi[c][kcol];
                bLo[nt] = *(const half8v*)&Bs_lo[c][kcol];
            }
#pragma unroll
            for (int mt = 0; mt < 2; ++mt)
#pragma unroll
                for (int nt = 0; nt < 2; ++nt) {
                    acc[mt][nt] = __builtin_amdgcn_mfma_f32_16x16x32_f16(
                        aHi[mt], bHi[nt], acc[mt][nt], 0, 0, 0);
                    acc[mt][nt] = __builtin_amdgcn_mfma_f32_16x16x32_f16(
                        aHi[mt], bLo[nt], acc[mt][nt], 0, 0, 0);
                    acc[mt][nt] = __builtin_amdgcn_mfma_f32_16x16x32_f16(
                        aLo[mt], bHi[nt], acc[mt][nt], 0, 0, 0);
                }
        }
    }

    int col0 = nBase + wn * 32 + l16;
    int col1 = col0 + 16;
    if (MODE == 0) {
        float b0 = bias[col0], b1v = bias[col1];
#pragma unroll
        for (int mt = 0; mt < 2; ++mt) {
#pragma unroll
            for (int r = 0; r < 4; ++r) {
                int row = mBase + wm * 32 + mt * 16 + quad * 4 + r;
                if (row >= M) continue;
                float o0 = acc[mt][0][r] + b0;
                float o1 = acc[mt][1][r] + b1v;
                _Float16 h0 = (_Float16)o0, h1 = (_Float16)o1;
                size_t p0 = (size_t)row * FDIM + col0;
                size_t p1 = (size_t)row * FDIM + col1;
                C_hi[p0] = h0;              C_hi[p1] = h1;
                C_lo[p0] = (_Float16)(o0 - (float)h0);
                C_lo[p1] = (_Float16)(o1 - (float)h1);
            }
        }
    } else {
        float as0 = a_src[col0], as1 = a_src[col1];
        float ad0 = a_dst[col0], ad1 = a_dst[col1];
#pragma unroll
        for (int mt = 0; mt < 2; ++mt) {
#pragma unroll
            for (int r = 0; r < 4; ++r) {
                int row = mBase + wm * 32 + mt * 16 + quad * 4 + r;
                if (row < M) {
                    C_hi[(size_t)row * FDIM + col0] = (_Float16)acc[mt][0][r];
                    C_hi[(size_t)row * FDIM + col1] = (_Float16)acc[mt][1][r];
                }
                float ps = acc[mt][0][r] * as0 + acc[mt][1][r] * as1;
                float pd = acc[mt][0][r] * ad0 + acc[mt][1][r] * ad1;
#pragma unroll
                for (int off = 8; off; off >>= 1) {
                    ps += __shfl_xor(ps, off);
                    pd += __shfl_xor(pd, off);
                }
                if (l16 == 0 && row < M) {
                    atomicAdd(&al_s[row], ps);
                    atomicAdd(&al_d[row], pd);
                }
            }
        }
    }
}

// ------- generic per-node softmax+aggregate (rare: deg > 128) --------------

__device__ __forceinline__ void agg_node_generic(
        const _Float16* __restrict__ t, const float* __restrict__ al_s,
        const int* __restrict__ srcs, int beg, int end, float ad, int lane,
        float4& acc, float& ssum) {
    const half4v* tb = (const half4v*)t + lane;
    float m = -INFINITY;
    for (int j = beg + lane; j < end; j += 64) {
        float ee = al_s[srcs[j]] + ad;
        ee = (ee > 0.f) ? ee : NEG_SLOPE * ee;
        m = fmaxf(m, ee);
    }
#pragma unroll
    for (int o = 32; o; o >>= 1) m = fmaxf(m, __shfl_xor(m, o));
    for (int jc = beg; jc < end; jc += 64) {
        int j = jc + lane;
        float ex = 0.f;
        int sr = 0;
        if (j < end) {
            int s = srcs[j];
            float ee = al_s[s] + ad;
            ee = (ee > 0.f) ? ee : NEG_SLOPE * ee;
            ex = __expf(ee - m);
            ssum += ex;
            sr = s * 64;
        }
        int cnt = min(64, end - jc);
        for (int jj = 0; jj < cnt; ++jj) {
            float a = __shfl(ex, jj);
            int r = __shfl(sr, jj);
            half4v v = tb[r];
            acc.x = fmaf(a, (float)v.x, acc.x); acc.y = fmaf(a, (float)v.y, acc.y);
            acc.z = fmaf(a, (float)v.z, acc.z); acc.w = fmaf(a, (float)v.w, acc.w);
        }
    }
}

// ------- fused edge-softmax + aggregation: 2 NODES PER WAVE ----------------
// (round-11 verified form: interleave saturates at 2 nodes/wave; 4 nodes
// blew the VGPR budget and regressed 26% — see round-12 post-mortem)

__global__ __launch_bounds__(256) void softagg(
        const _Float16* __restrict__ t, const float* __restrict__ al_s,
        const float* __restrict__ al_d, const int* __restrict__ row_ptr,
        const int* __restrict__ srcs, const float* __restrict__ bias,
        _Float16* __restrict__ out_hi, _Float16* __restrict__ out_lo, int N) {
    int wave = threadIdx.x >> 6, lane = threadIdx.x & 63;
    int nodeA = blockIdx.x * 8 + wave * 2;
    if (nodeA >= N) return;
    int nodeB = nodeA + 1;
    bool hasB = nodeB < N;

    int begA = row_ptr[nodeA], endA = row_ptr[nodeA + 1];
    int begB = 0, endB = 0;
    if (hasB) { begB = endA; endB = row_ptr[nodeB + 1]; }  // CSR contiguity
    int degA = endA - begA, degB = endB - begB;
    float adA = al_d[nodeA];
    float adB = hasB ? al_d[nodeB] : 0.f;

    const half4v* tb = (const half4v*)t + lane;
    float4 accA = make_float4(0.f, 0.f, 0.f, 0.f);
    float4 accB = make_float4(0.f, 0.f, 0.f, 0.f);
    float ssumA = 0.f, ssumB = 0.f;

    if (degA <= 128 && degB <= 128) {
        // ---- phase 1: e values for both nodes ----
        float eA[2], eB[2];
        int sjA[2], sjB[2];
#pragma unroll
        for (int c = 0; c < 2; ++c) {
            eA[c] = -INFINITY; sjA[c] = 0;
            int j = begA + c * 64 + lane;
            if (j < endA) {
                int s = srcs[j];
                float ee = al_s[s] + adA;
                eA[c] = (ee > 0.f) ? ee : NEG_SLOPE * ee;
                sjA[c] = s * 64;
            }
            eB[c] = -INFINITY; sjB[c] = 0;
            int jb = begB + c * 64 + lane;
            if (hasB && jb < endB) {
                int s = srcs[jb];
                float ee = al_s[s] + adB;
                eB[c] = (ee > 0.f) ? ee : NEG_SLOPE * ee;
                sjB[c] = s * 64;
            }
        }
        float mA = fmaxf(eA[0], eA[1]);
        float mB = fmaxf(eB[0], eB[1]);
#pragma unroll
        for (int o = 32; o; o >>= 1) {
            mA = fmaxf(mA, __shfl_xor(mA, o));
            mB = fmaxf(mB, __shfl_xor(mB, o));
        }
        float exA[2], exB[2];
#pragma unroll
        for (int c = 0; c < 2; ++c) {
            exA[c] = (eA[c] == -INFINITY) ? 0.f : __expf(eA[c] - mA);
            ssumA += exA[c];
            exB[c] = (eB[c] == -INFINITY) ? 0.f : __expf(eB[c] - mB);
            ssumB += exB[c];
        }

        // ---- gather: chunk 0 of A and B interleaved (common case) ----
        int cntA0 = min(64, degA);            // >=1 (self-loop)
        int cntB0 = min(64, max(degB, 0));
        int ngA = (cntA0 + 3) >> 2;
        int ngB = (cntB0 + 3) >> 2;
        int ng = max(ngA, ngB);
        for (int g = 0; g < ng; ++g) {
            int jj = g * 4;
            if (g < ngA) {
                float a0 = __shfl(exA[0], jj + 0), a1 = __shfl(exA[0], jj + 1);
                float a2 = __shfl(exA[0], jj + 2), a3 = __shfl(exA[0], jj + 3);
                int r0 = __shfl(sjA[0], jj + 0), r1 = __shfl(sjA[0], jj + 1);
                int r2 = __shfl(sjA[0], jj + 2), r3 = __shfl(sjA[0], jj + 3);
                half4v v0 = tb[r0], v1 = tb[r1], v2 = tb[r2], v3 = tb[r3];
                accA.x = fmaf(a0, (float)v0.x, accA.x); accA.y = fmaf(a0, (float)v0.y, accA.y);
                accA.z = fmaf(a0, (float)v0.z, accA.z); accA.w = fmaf(a0, (float)v0.w, accA.w);
                accA.x = fmaf(a1, (float)v1.x, accA.x); accA.y = fmaf(a1, (float)v1.y, accA.y);
                accA.z = fmaf(a1, (float)v1.z, accA.z); accA.w = fmaf(a1, (float)v1.w, accA.w);
                accA.x = fmaf(a2, (float)v2.x, accA.x); accA.y = fmaf(a2, (float)v2.y, accA.y);
                accA.z = fmaf(a2, (float)v2.z, accA.z); accA.w = fmaf(a2, (float)v2.w, accA.w);
                accA.x = fmaf(a3, (float)v3.x, accA.x); accA.y = fmaf(a3, (float)v3.y, accA.y);
                accA.z = fmaf(a3, (float)v3.z, accA.z); accA.w = fmaf(a3, (float)v3.w, accA.w);
            }
            if (g < ngB) {
                float a0 = __shfl(exB[0], jj + 0), a1 = __shfl(exB[0], jj + 1);
                float a2 = __shfl(exB[0], jj + 2), a3 = __shfl(exB[0], jj + 3);
                int r0 = __shfl(sjB[0], jj + 0), r1 = __shfl(sjB[0], jj + 1);
                int r2 = __shfl(sjB[0], jj + 2), r3 = __shfl(sjB[0], jj + 3);
                half4v v0 = tb[r0], v1 = tb[r1], v2 = tb[r2], v3 = tb[r3];
                accB.x = fmaf(a0, (float)v0.x, accB.x); accB.y = fmaf(a0, (float)v0.y, accB.y);
                accB.z = fmaf(a0, (float)v0.z, accB.z); accB.w = fmaf(a0, (float)v0.w, accB.w);
                accB.x = fmaf(a1, (float)v1.x, accB.x); accB.y = fmaf(a1, (float)v1.y, accB.y);
                accB.z = fmaf(a1, (float)v1.z, accB.z); accB.w = fmaf(a1, (float)v1.w, accB.w);
                accB.x = fmaf(a2, (float)v2.x, accB.x); accB.y = fmaf(a2, (float)v2.y, accB.y);
                accB.z = fmaf(a2, (float)v2.z, accB.z); accB.w = fmaf(a2, (float)v2.w, accB.w);
                accB.x = fmaf(a3, (float)v3.x, accB.x); accB.y = fmaf(a3, (float)v3.y, accB.y);
                accB.z = fmaf(a3, (float)v3.z, accB.z); accB.w = fmaf(a3, (float)v3.w, accB.w);
            }
        }
        // ---- rare chunk-1 (64 < deg <= 128) ----
        if (degA > 64) {
            int ng1 = ((degA - 64) + 3) >> 2;
            for (int g = 0; g < ng1; ++g) {
                int jj = g * 4;
#pragma unroll
                for (int q = 0; q < 4; ++q) {
                    float a = __shfl(exA[1], jj + q);
                    int r = __shfl(sjA[1], jj + q);
                    half4v v = tb[r];
                    accA.x = fmaf(a, (float)v.x, accA.x); accA.y = fmaf(a, (float)v.y, accA.y);
                    accA.z = fmaf(a, (float)v.z, accA.z); accA.w = fmaf(a, (float)v.w, accA.w);
                }
            }
        }
        if (degB > 64) {
            int ng1 = ((degB - 64) + 3) >> 2;
            for (int g = 0; g < ng1; ++g) {
                int jj = g * 4;
#pragma unroll
                for (int q = 0; q < 4; ++q) {
                    float a = __shfl(exB[1], jj + q);
                    int r = __shfl(sjB[1], jj + q);
                    half4v v = tb[r];
                    accB.x = fmaf(a, (float)v.x, accB.x); accB.y = fmaf(a, (float)v.y, accB.y);
                    accB.z = fmaf(a, (float)v.z, accB.z); accB.w = fmaf(a, (float)v.w, accB.w);
                }
            }
        }
    } else {
        agg_node_generic(t, al_s, srcs, begA, endA, adA, lane, accA, ssumA);
        if (hasB) agg_node_generic(t, al_s, srcs, begB, endB, adB, lane, accB, ssumB);
    }

#pragma unroll
    for (int o = 32; o; o >>= 1) {
        ssumA += __shfl_xor(ssumA, o);
        ssumB += __shfl_xor(ssumB, o);
    }
    float4 bv = ((const float4*)bias)[lane];
    {
        float inv = 1.f / (ssumA + 1e-16f);
        float ox = fmaf(accA.x, inv, bv.x);
        float oy = fmaf(accA.y, inv, bv.y);
        float oz = fmaf(accA.z, inv, bv.z);
        float ow = fmaf(accA.w, inv, bv.w);
        _Float16 hx = (_Float16)ox, hy = (_Float16)oy;
        _Float16 hz = (_Float16)oz, hw = (_Float16)ow;
        half4v hi = {hx, hy, hz, hw};
        *(half4v*)(out_hi + (size_t)nodeA * FDIM + lane * 4) = hi;
        if (out_lo) {
            half4v lo = {(_Float16)(ox - (float)hx), (_Float16)(oy - (float)hy),
                         (_Float16)(oz - (float)hz), (_Float16)(ow - (float)hw)};
            *(half4v*)(out_lo + (size_t)nodeA * FDIM + lane * 4) = lo;
        }
    }
    if (hasB) {
        float inv = 1.f / (ssumB + 1e-16f);
        float ox = fmaf(accB.x, inv, bv.x);
        float oy = fmaf(accB.y, inv, bv.y);
        float oz = fmaf(accB.z, inv, bv.z);
        float ow = fmaf(accB.w, inv, bv.w);
        _Float16 hx = (_Float16)ox, hy = (_Float16)oy;
        _Float16 hz = (_Float16)oz, hw = (_Float16)ow;
        half4v hi = {hx, hy, hz, hw};
        *(half4v*)(out_hi + (size_t)nodeB * FDIM + lane * 4) = hi;
        if (out_lo) {
            half4v lo = {(_Float16)(ox - (float)hx), (_Float16)(oy - (float)hy),
                         (_Float16)(oz - (float)hz), (_Float16)(ow - (float)hw)};
            *(half4v*)(out_lo + (size_t)nodeB * FDIM + lane * 4) = lo;
        }
    }
}

// -------- logits: 4 edges per wave, f16 h rows (half4/lane) ----------------

__global__ __launch_bounds__(256) void edge_dot(const _Float16* __restrict__ h,
                                                const int* __restrict__ ei,
                                                float* __restrict__ out, int EQ) {
    int w = threadIdx.x >> 6, lane = threadIdx.x & 63;
    int e0 = (blockIdx.x * 4 + w) * 4;
    if (e0 >= EQ) return;
    int u[4], v[4];
    if (e0 + 3 < EQ && ((EQ & 3) == 0)) {
        int4 uu = *(const int4*)(ei + e0);
        int4 vv = *(const int4*)(ei + EQ + e0);
        u[0] = uu.x; u[1] = uu.y; u[2] = uu.z; u[3] = uu.w;
        v[0] = vv.x; v[1] = vv.y; v[2] = vv.z; v[3] = vv.w;
    } else {
#pragma unroll
        for (int q = 0; q < 4; ++q) {
            int e = min(e0 + q, EQ - 1);
            u[q] = ei[e];
            v[q] = ei[EQ + e];
        }
    }
    const half4v* hb = (const half4v*)h + lane;
    float s[4];
#pragma unroll
    for (int q = 0; q < 4; ++q) {
        half4v a = hb[(size_t)u[q] * 64];
        half4v b = hb[(size_t)v[q] * 64];
        s[q] = (float)a.x * (float)b.x + (float)a.y * (float)b.y +
               (float)a.z * (float)b.z + (float)a.w * (float)b.w;
    }
#pragma unroll
    for (int o = 32; o; o >>= 1) {
        s[0] += __shfl_down(s[0], o);
        s[1] += __shfl_down(s[1], o);
        s[2] += __shfl_down(s[2], o);
        s[3] += __shfl_down(s[3], o);
    }
    if (lane == 0) {
#pragma unroll
        for (int q = 0; q < 4; ++q)
            if (e0 + q < EQ) out[e0 + q] = s[q];
    }
}

// ---------------------------------------------------------------------------

extern "C" void kernel_launch(void* const* d_in, const int* in_sizes, int n_in,
                              void* d_out, int out_size, void* d_ws, size_t ws_size,
                              hipStream_t stream) {
    const float* x       = (const float*)d_in[0];
    const int*   pos_ei  = (const int*)d_in[1];
    const int*   q_ei    = (const int*)d_in[2];
    const float* Win_W   = (const float*)d_in[3];
    const float* Win_b   = (const float*)d_in[4];
    const float* W1      = (const float*)d_in[5];
    const float* a1_src  = (const float*)d_in[6];
    const float* a1_dst  = (const float*)d_in[7];
    const float* b1      = (const float*)d_in[8];
    const float* W2      = (const float*)d_in[9];
    const float* a2_src  = (const float*)d_in[10];
    const float* a2_dst  = (const float*)d_in[11];
    const float* b2      = (const float*)d_in[12];
    float* logits = (float*)d_out;

    const int N = in_sizes[0] / FDIM;   // 10000
    const int E_pos = in_sizes[1] / 2;  // 320000
    const int EQ = in_sizes[2] / 2;     // 100000
    const int E_tot = E_pos + N;        // 330000
    const size_t WMAT = (size_t)FDIM * FDIM;
    const size_t NF = (size_t)N * FDIM;

    // workspace carve-up
    _Float16* Wt_hi = (_Float16*)d_ws;          // 3*WMAT
    _Float16* Wt_lo = Wt_hi + 3 * WMAT;         // 3*WMAT
    _Float16* h0_hi = Wt_lo + 3 * WMAT;         // NF (also o2_hi)
    _Float16* h0_lo = h0_hi + NF;               // NF (also o2_lo)
    _Float16* t_h   = h0_lo + NF;               // NF
    _Float16* h16   = t_h + NF;                 // NF f16 (final h for edge_dot)
    float* al_s1 = (float*)(h16 + NF);          // N -- zero region start
    float* al_d1 = al_s1 + N;                   // N
    float* al_s2 = al_d1 + N;                   // N
    float* al_d2 = al_s2 + N;                   // N
    int* cnt     = (int*)(al_d2 + N);           // N -- zero region end
    int* row_ptr = cnt + N;                     // N+1
    int* fill    = row_ptr + (N + 1);           // N
    int* srcs    = fill + N;                    // E_tot

    hipMemsetAsync(al_s1, 0, (size_t)(4 * N) * sizeof(float) + (size_t)N * sizeof(int), stream);

    int nbE = (E_tot + 255) / 256;      // 1290
    int mblk = (N + 63) / 64;           // 157
    int nbGemm = mblk * (FDIM / 64);    // 628
    int nblk8 = (N + 7) / 8;            // 1250

    // ---- D1: histogram + weight prep ----
    build_phase1<<<nbE + 768, 256, 0, stream>>>(pos_ei, cnt, Win_W, W1, W2,
                                                Wt_hi, Wt_lo, E_pos, E_tot, nbE);

    // ---- D2: gemm<0> (h0 = x @ Win + b) + sidecar CSR scan ----
    gemm_mfma<0><<<nbGemm + 1, 256, 0, stream>>>(
        x, nullptr, nullptr, Wt_hi, Wt_lo, Win_b,
        nullptr, nullptr, nullptr, nullptr, h0_hi, h0_lo,
        N, nbGemm, mblk,
        pos_ei, cnt, row_ptr, fill, E_pos, E_tot, N);

    // ---- D3: gemm<1> L1 (t = h0 @ W1, attn -> al1) + sidecar edge scatter ----
    gemm_mfma<1><<<nbGemm + nbE, 256, 0, stream>>>(
        nullptr, h0_hi, h0_lo, Wt_hi + WMAT, Wt_lo + WMAT, nullptr,
        a1_src, a1_dst, al_s1, al_d1, t_h, nullptr,
        N, nbGemm, mblk,
        pos_ei, fill, nullptr, srcs, E_pos, E_tot, N);

    // ---- D4: softagg L1 -> o2 split (aliases h0), 2 nodes/wave ----
    softagg<<<nblk8, 256, 0, stream>>>(t_h, al_s1, al_d1, row_ptr, srcs, b1,
                                       h0_hi, h0_lo, N);

    // ---- D5: gemm<1> L2 (t = o2 @ W2, attn -> al2) ----
    gemm_mfma<1><<<nbGemm, 256, 0, stream>>>(
        nullptr, h0_hi, h0_lo, Wt_hi + 2 * WMAT, Wt_lo + 2 * WMAT, nullptr,
        a2_src, a2_dst, al_s2, al_d2, t_h, nullptr,
        N, nbGemm, mblk,
        nullptr, nullptr, nullptr, nullptr, 0, 0, N);

    // ---- D6: softagg L2 -> h16 (plain f16), 2 nodes/wave ----
    softagg<<<nblk8, 256, 0, stream>>>(t_h, al_s2, al_d2, row_ptr, srcs, b2,
                                       h16, nullptr, N);

    // ---- D7: logits (4 edges/wave, f16 rows) ----
    edge_dot<<<(EQ + 15) / 16, 256, 0, stream>>>(h16, q_ei, logits, EQ);
}